// Round 4
// baseline (480.235 us; speedup 1.0000x reference)
//
#include <hip/hip_runtime.h>
#include <hip/hip_bf16.h>
#include <math.h>

// Problem constants
#define BB 4
#define CC 256
#define NN 4096          // H*W
#define EE 96
#define NTOT (BB*NN)     // 16384 rows

typedef __attribute__((ext_vector_type(8))) short bf16x8;
typedef __attribute__((ext_vector_type(4))) float f32x4;

__device__ __forceinline__ short f2bf(float x) {
    __hip_bfloat16 h = __float2bfloat16(x);
    return *reinterpret_cast<short*>(&h);
}
__device__ __forceinline__ float bf2f(short s) {
    unsigned int u = ((unsigned int)(unsigned short)s) << 16;
    float f;
    __builtin_memcpy(&f, &u, 4);
    return f;
}
__device__ __forceinline__ float gelu_exact(float v) {
    return 0.5f * v * (1.0f + erff(v * 0.70710678118654752f));
}

// Weight arena offsets (shorts). wg split into aligned 256-stride matrix + last col.
#define OFF_WQ  0
#define OFF_WK  24576
#define OFF_WV  49152
#define OFF_WO  114688
#define OFF_WD1 180224
#define OFF_WD2 311296
#define OFF_WG  376832
#define OFF_WGL 442368
#define W16_TOTAL 442624

// ---------------------------------------------------------------------------
// Weight fp32 -> bf16 converter
// ---------------------------------------------------------------------------
__global__ void wconv_kernel(const float* __restrict__ wq, const float* __restrict__ wk,
                             const float* __restrict__ wv, const float* __restrict__ wo,
                             const float* __restrict__ wd1, const float* __restrict__ wd2,
                             const float* __restrict__ wg, short* __restrict__ W16) {
    int i = blockIdx.x * 256 + threadIdx.x;
    if (i >= W16_TOTAL) return;
    float v;
    if      (i < OFF_WK)  v = wq[i];
    else if (i < OFF_WV)  v = wk[i - OFF_WK];
    else if (i < OFF_WO)  v = wv[i - OFF_WV];
    else if (i < OFF_WD1) v = wo[i - OFF_WO];
    else if (i < OFF_WD2) v = wd1[i - OFF_WD1];
    else if (i < OFF_WG)  v = wd2[i - OFF_WD2];
    else if (i < OFF_WGL) { int l = i - OFF_WG; v = wg[(l >> 8) * 257 + (l & 255)]; }
    else                  v = wg[(i - OFF_WGL) * 257 + 256];
    W16[i] = f2bf(v);
}

// ---------------------------------------------------------------------------
// Kernel 1: channel LayerNorm + transpose; emits bf16 Xt16, Xn16, Xnm16
// ---------------------------------------------------------------------------
__global__ void ln_kernel(const float* __restrict__ x,
                          const float* __restrict__ gamma,
                          const float* __restrict__ beta,
                          const float* __restrict__ mask,
                          short* __restrict__ Xt16, short* __restrict__ Xn16,
                          short* __restrict__ Xnm16) {
    __shared__ float tile[256 * 65];
    __shared__ float psum[4][64], psq[4][64];
    __shared__ float mu_s[64], rs_s[64], mk_s[64];
    __shared__ float gs[256], bs[256];
    const int b  = blockIdx.x >> 6;
    const int p0 = (blockIdx.x & 63) * 64;
    const int tid = threadIdx.x;
    const float* xb = x + (size_t)b * CC * NN;

    gs[tid] = gamma[tid];
    bs[tid] = beta[tid];
    #pragma unroll
    for (int i = 0; i < 16; ++i) {
        int idx = tid + i * 256;
        int c = idx >> 4, p4 = (idx & 15) * 4;
        float4 v = *(const float4*)&xb[(size_t)c * NN + p0 + p4];
        tile[c * 65 + p4]     = v.x;
        tile[c * 65 + p4 + 1] = v.y;
        tile[c * 65 + p4 + 2] = v.z;
        tile[c * 65 + p4 + 3] = v.w;
    }
    if (tid < 64) mk_s[tid] = mask[(size_t)b * NN + p0 + tid];
    __syncthreads();
    {
        int col = tid & 63, part = tid >> 6;
        float s = 0.f, sq = 0.f;
        for (int r = part * 64; r < part * 64 + 64; ++r) {
            float v = tile[r * 65 + col];
            s += v; sq += v * v;
        }
        psum[part][col] = s; psq[part][col] = sq;
    }
    __syncthreads();
    if (tid < 64) {
        float S  = psum[0][tid] + psum[1][tid] + psum[2][tid] + psum[3][tid];
        float SQ = psq[0][tid] + psq[1][tid] + psq[2][tid] + psq[3][tid];
        float mu = S / 256.0f;
        float var = SQ / 256.0f - mu * mu;
        mu_s[tid] = mu;
        rs_s[tid] = rsqrtf(var + 1e-5f);
    }
    __syncthreads();
    size_t rowbase = ((size_t)b * NN + p0) * CC;
    #pragma unroll
    for (int i = 0; i < 8; ++i) {
        int idx = tid + i * 256;
        int p = idx >> 5, c8 = (idx & 31) * 8;
        float mu = mu_s[p], rcp = rs_s[p], mk = mk_s[p];
        bf16x8 xt, xn, xm;
        #pragma unroll
        for (int j = 0; j < 8; ++j) {
            float v = tile[(c8 + j) * 65 + p];
            float n = (v - mu) * rcp * gs[c8 + j] + bs[c8 + j];
            xt[j] = f2bf(v); xn[j] = f2bf(n); xm[j] = f2bf(n * mk);
        }
        size_t o = rowbase + (size_t)p * CC + c8;
        *(bf16x8*)&Xt16[o]  = xt;
        *(bf16x8*)&Xn16[o]  = xn;
        *(bf16x8*)&Xnm16[o] = xm;
    }
}

// ---------------------------------------------------------------------------
// Kernel 2: fused Q+K projection + cosine norm -> bf16 Q16, K16.
// N=192 (96 Q cols | 96 K cols), K=256, per-wave 16 rows; in-register L2 norm.
// ---------------------------------------------------------------------------
__global__ __launch_bounds__(256) void qkproj_kernel(
    const short* __restrict__ Xn16, const short* __restrict__ W16,
    const float* __restrict__ mask, const float* __restrict__ w_qm,
    short* __restrict__ Q16, short* __restrict__ K16)
{
    __shared__ short As[64 * 40];
    __shared__ short Ws[192 * 40];
    const int tid = threadIdx.x;
    const int w = tid >> 6, lane = tid & 63, ln = lane & 15, quad = lane >> 4;
    const int m0 = blockIdx.x * 64;

    f32x4 acc[12];
    #pragma unroll
    for (int i = 0; i < 12; ++i) acc[i] = (f32x4){0.f, 0.f, 0.f, 0.f};

    for (int kt = 0; kt < 8; ++kt) {
        const int k0 = kt * 32;
        __syncthreads();
        {
            int m = tid >> 2, kc = tid & 3;
            *(bf16x8*)&As[m * 40 + kc * 8] =
                *(const bf16x8*)&Xn16[(size_t)(m0 + m) * 256 + k0 + kc * 8];
        }
        for (int i = tid; i < 768; i += 256) {
            int n = i >> 2, kc = i & 3;
            const short* src = (n < 96) ? &W16[OFF_WQ + (size_t)n * 256 + k0 + kc * 8]
                                        : &W16[OFF_WK + (size_t)(n - 96) * 256 + k0 + kc * 8];
            *(bf16x8*)&Ws[n * 40 + kc * 8] = *(const bf16x8*)src;
        }
        __syncthreads();
        bf16x8 af = *(const bf16x8*)&As[(w * 16 + ln) * 40 + quad * 8];
        #pragma unroll
        for (int nt = 0; nt < 12; ++nt) {
            bf16x8 bf = *(const bf16x8*)&Ws[(nt * 16 + ln) * 40 + quad * 8];
            acc[nt] = __builtin_amdgcn_mfma_f32_16x16x32_bf16(af, bf, acc[nt], 0, 0, 0);
        }
    }

    const int rowb = m0 + w * 16 + quad * 4;
    #pragma unroll
    for (int r = 0; r < 4; ++r) {
        int row = rowb + r;
        float mrow = mask[row];
        float q[6], k[6];
        float ssq = 0.f, ssk = 0.f;
        #pragma unroll
        for (int nt = 0; nt < 6; ++nt) {
            q[nt] = acc[nt][r] + mrow * w_qm[nt * 16 + ln];
            ssq += q[nt] * q[nt];
            k[nt] = acc[6 + nt][r];
            ssk += k[nt] * k[nt];
        }
        ssq += __shfl_xor(ssq, 1, 64); ssk += __shfl_xor(ssk, 1, 64);
        ssq += __shfl_xor(ssq, 2, 64); ssk += __shfl_xor(ssk, 2, 64);
        ssq += __shfl_xor(ssq, 4, 64); ssk += __shfl_xor(ssk, 4, 64);
        ssq += __shfl_xor(ssq, 8, 64); ssk += __shfl_xor(ssk, 8, 64);
        float sq = 1.0f / fmaxf(sqrtf(ssq), 1e-12f);
        float sk = 1.0f / fmaxf(sqrtf(ssk), 1e-12f);
        #pragma unroll
        for (int nt = 0; nt < 6; ++nt) {
            Q16[(size_t)row * EE + nt * 16 + ln] = f2bf(q[nt] * sq);
            K16[(size_t)row * EE + nt * 16 + ln] = f2bf(k[nt] * sk);
        }
    }
}

// ---------------------------------------------------------------------------
// Kernel 2b (template kept for V-proj MODE 2 and wd1 MODE 4)
// ---------------------------------------------------------------------------
template <int NT, int KT, int MODE>
__global__ __launch_bounds__(256) void mgemm(
    const short* __restrict__ A16, const short* __restrict__ A16b,
    const short* __restrict__ W16, int ldw,
    short* __restrict__ outb)
{
    constexpr int K = KT * 32;
    __shared__ short As[64 * 40];
    __shared__ short Ws[NT * 16 * 40];
    const int tid = threadIdx.x;
    const int w = tid >> 6, lane = tid & 63, ln = lane & 15, quad = lane >> 4;
    const int m0 = blockIdx.x * 64;

    f32x4 acc[NT];
    #pragma unroll
    for (int i = 0; i < NT; ++i) acc[i] = (f32x4){0.f, 0.f, 0.f, 0.f};

    for (int kt = 0; kt < KT; ++kt) {
        const int k0 = kt * 32;
        __syncthreads();
        {
            int m = tid >> 2, kc = tid & 3;
            int kk = k0 + kc * 8;
            const short* src;
            if (MODE == 4) {
                src = (kk < 256) ? &A16[(size_t)(m0 + m) * 256 + kk]
                                 : &A16b[(size_t)(m0 + m) * 256 + kk - 256];
            } else {
                src = &A16[(size_t)(m0 + m) * K + kk];
            }
            *(bf16x8*)&As[m * 40 + kc * 8] = *(const bf16x8*)src;
        }
        for (int i = tid; i < NT * 64; i += 256) {
            int n = i >> 2, kc = i & 3;
            *(bf16x8*)&Ws[n * 40 + kc * 8] =
                *(const bf16x8*)&W16[(size_t)n * ldw + k0 + kc * 8];
        }
        __syncthreads();
        bf16x8 af = *(const bf16x8*)&As[(w * 16 + ln) * 40 + quad * 8];
        #pragma unroll
        for (int nt = 0; nt < NT; ++nt) {
            bf16x8 bf = *(const bf16x8*)&Ws[(nt * 16 + ln) * 40 + quad * 8];
            acc[nt] = __builtin_amdgcn_mfma_f32_16x16x32_bf16(af, bf, acc[nt], 0, 0, 0);
        }
    }

    const int rowb = m0 + w * 16 + quad * 4;
    if (MODE == 4) {
        #pragma unroll
        for (int nt = 0; nt < NT; ++nt) {
            int col = nt * 16 + ln;
            #pragma unroll
            for (int r = 0; r < 4; ++r)
                outb[(size_t)(rowb + r) * 256 + col] = f2bf(gelu_exact(acc[nt][r]));
        }
    } else if (MODE == 2) {     // V: transpose to [B, C, N] bf16
        short* tileT = Ws;
        const int b = m0 >> 12, p0l = m0 & 4095;
        for (int g = 0; g < 4; ++g) {
            __syncthreads();
            #pragma unroll
            for (int j = 0; j < 4; ++j) {
                #pragma unroll
                for (int r = 0; r < 4; ++r)
                    tileT[(j * 16 + ln) * 66 + (w * 16 + quad * 4 + r)] =
                        f2bf(acc[g * 4 + j][r]);
            }
            __syncthreads();
            for (int e = tid; e < 2048; e += 256) {
                int ch = e >> 5, pp = (e & 31) * 2;
                unsigned lo = (unsigned short)tileT[ch * 66 + pp];
                unsigned hi = (unsigned short)tileT[ch * 66 + pp + 1];
                *(unsigned*)&outb[((size_t)b * CC + g * 64 + ch) * NN + p0l + pp] =
                    lo | (hi << 16);
            }
        }
    }
}

// ---------------------------------------------------------------------------
// Kernel 3: barrier-free MFMA attention + fused w_out epilogue.
// 1024 blocks x 4 waves; wave w: 16 queries x keys [w*1024, w*1024+1024).
// Fixed-max softmax (cosine scores bounded) -> associative K-split.
// Epilogue: cross-wave O reduce -> O@wo^T - Xt -> D1in.
// ---------------------------------------------------------------------------
__global__ __launch_bounds__(256, 4) void attn3_kernel(
    const short* __restrict__ Q16, const short* __restrict__ K16,
    const short* __restrict__ V16t, const float* __restrict__ mask,
    const short* __restrict__ W16, const short* __restrict__ Xt16,
    short* __restrict__ D1in)
{
    __shared__ char lds[25088];
    short* Ps   = (short*)lds;                 // loop: 4 waves x 640 shorts
    float* Red  = (float*)lds;                 // epilogue: 16KB (overlaps Ps)
    float* LRed = (float*)(lds + 16384);       // 64 floats
    short* Olds = (short*)(lds + 16640);       // 16 x 264 bf16

    const int tid = threadIdx.x;
    const int w = tid >> 6, lane = tid & 63, ln = lane & 15, quad = lane >> 4;
    const int bidx = blockIdx.x;
    const int b  = (bidx & 7) >> 1;                    // XCD-pinned batch
    const int qt = ((bidx >> 3) << 1) | (bidx & 1);    // 0..255
    const int q0 = qt * 16;
    const size_t bN = (size_t)b * NN;
    const float C1 = 1.02062072615966f;                // 10/sqrt(96)

    bf16x8 qf[3];
    #pragma unroll
    for (int e = 0; e < 3; ++e)
        qf[e] = *(const bf16x8*)&Q16[(bN + q0 + ln) * EE + e * 32 + quad * 8];

    f32x4 acc[16];
    #pragma unroll
    for (int ct = 0; ct < 16; ++ct) acc[ct] = (f32x4){0.f, 0.f, 0.f, 0.f};
    float lsum[4] = {0.f, 0.f, 0.f, 0.f};

    short* Pw = Ps + w * 640;

    for (int it = 0; it < 32; ++it) {
        const int k0 = w * 1024 + it * 32;
        float mk0 = mask[bN + k0 + ln];
        float mk1 = mask[bN + k0 + 16 + ln];
        f32x4 s0 = (f32x4){0.f,0.f,0.f,0.f}, s1 = s0;
        #pragma unroll
        for (int e = 0; e < 3; ++e) {
            bf16x8 kf0 = *(const bf16x8*)&K16[(bN + k0 + ln) * EE + e * 32 + quad * 8];
            bf16x8 kf1 = *(const bf16x8*)&K16[(bN + k0 + 16 + ln) * EE + e * 32 + quad * 8];
            s0 = __builtin_amdgcn_mfma_f32_16x16x32_bf16(qf[e], kf0, s0, 0, 0, 0);
            s1 = __builtin_amdgcn_mfma_f32_16x16x32_bf16(qf[e], kf1, s1, 0, 0, 0);
        }
        bool z0 = mk0 >= 0.5f, z1 = mk1 >= 0.5f;
        #pragma unroll
        for (int r = 0; r < 4; ++r) {
            float p0 = z0 ? 0.f : __expf(fmaf(s0[r], C1, -C1));
            float p1 = z1 ? 0.f : __expf(fmaf(s1[r], C1, -C1));
            lsum[r] += p0 + p1;
            Pw[(quad * 4 + r) * 40 + ln]      = f2bf(p0);
            Pw[(quad * 4 + r) * 40 + 16 + ln] = f2bf(p1);
        }
        bf16x8 pf = *(const bf16x8*)&Pw[ln * 40 + quad * 8];
        #pragma unroll
        for (int ct = 0; ct < 16; ++ct) {
            bf16x8 vf = *(const bf16x8*)&V16t[((size_t)b * CC + ct * 16 + ln) * NN + k0 + quad * 8];
            acc[ct] = __builtin_amdgcn_mfma_f32_16x16x32_bf16(pf, vf, acc[ct], 0, 0, 0);
        }
    }

    // per-wave l over its 1024 keys
    #pragma unroll
    for (int r = 0; r < 4; ++r) {
        float l = lsum[r];
        l += __shfl_xor(l, 1, 64); l += __shfl_xor(l, 2, 64);
        l += __shfl_xor(l, 4, 64); l += __shfl_xor(l, 8, 64);
        LRed[w * 16 + quad * 4 + r] = l;
    }

    // serial cross-wave O reduction (Ps dead after this barrier)
    __syncthreads();
    if (w == 3) {
        #pragma unroll
        for (int ct = 0; ct < 16; ++ct)
            *(f32x4*)&Red[ct * 256 + lane * 4] = acc[ct];
    }
    __syncthreads();
    if (w == 2) {
        #pragma unroll
        for (int ct = 0; ct < 16; ++ct) {
            acc[ct] += *(f32x4*)&Red[ct * 256 + lane * 4];
            *(f32x4*)&Red[ct * 256 + lane * 4] = acc[ct];
        }
    }
    __syncthreads();
    if (w == 1) {
        #pragma unroll
        for (int ct = 0; ct < 16; ++ct) {
            acc[ct] += *(f32x4*)&Red[ct * 256 + lane * 4];
            *(f32x4*)&Red[ct * 256 + lane * 4] = acc[ct];
        }
    }
    __syncthreads();
    if (w == 0) {
        float linv[4];
        #pragma unroll
        for (int r = 0; r < 4; ++r) {
            int qi = quad * 4 + r;
            linv[r] = 1.0f / (LRed[qi] + LRed[16 + qi] + LRed[32 + qi] + LRed[48 + qi]);
        }
        #pragma unroll
        for (int ct = 0; ct < 16; ++ct) {
            acc[ct] += *(f32x4*)&Red[ct * 256 + lane * 4];
            #pragma unroll
            for (int r = 0; r < 4; ++r)
                Olds[(quad * 4 + r) * 264 + ct * 16 + ln] = f2bf(acc[ct][r] * linv[r]);
        }
    }
    __syncthreads();

    // fused w_out: D1 = O @ wo^T - Xt   (wave w owns cols [w*64, w*64+64))
    f32x4 acc2[4];
    #pragma unroll
    for (int i = 0; i < 4; ++i) acc2[i] = (f32x4){0.f, 0.f, 0.f, 0.f};
    #pragma unroll
    for (int kt = 0; kt < 8; ++kt) {
        bf16x8 af = *(const bf16x8*)&Olds[ln * 264 + kt * 32 + quad * 8];
        #pragma unroll
        for (int nt = 0; nt < 4; ++nt) {
            int col = w * 64 + nt * 16 + ln;
            bf16x8 bf = *(const bf16x8*)&W16[OFF_WO + (size_t)col * 256 + kt * 32 + quad * 8];
            acc2[nt] = __builtin_amdgcn_mfma_f32_16x16x32_bf16(af, bf, acc2[nt], 0, 0, 0);
        }
    }
    #pragma unroll
    for (int nt = 0; nt < 4; ++nt) {
        int col = w * 64 + nt * 16 + ln;
        #pragma unroll
        for (int r = 0; r < 4; ++r) {
            size_t row = bN + q0 + quad * 4 + r;
            D1in[row * 256 + col] =
                f2bf(acc2[nt][r] - bf2f(Xt16[row * 256 + col]));
        }
    }
}

// ---------------------------------------------------------------------------
// Kernel 5: fused wd2 + gate (wg) + residual writeback.
// Phase 1: Cor = Hid @ wd2^T (64 x 256 full-width tile, kept in LDS only).
// Phase 2: logit = Cor @ wg^T (+mask*wg_last); delta = tanh(rs)*gate*Cor;
//          out[b,c,p] = x + delta (transpose through LDS).
// ---------------------------------------------------------------------------
__global__ __launch_bounds__(256) void final_kernel(
    const short* __restrict__ Hid16, const short* __restrict__ W16,
    const float* __restrict__ mask, const float* __restrict__ rs,
    const float* __restrict__ x, float* __restrict__ out)
{
    __shared__ short As[64 * 40];       // 5120 B
    __shared__ short Ws[256 * 40];      // 20480 B (also tileF in epilogue)
    __shared__ short Clds[64 * 264];    // 33792 B
    const int tid = threadIdx.x;
    const int w = tid >> 6, lane = tid & 63, ln = lane & 15, quad = lane >> 4;
    const int m0 = blockIdx.x * 64;

    // ---- Phase 1: Cor tile ----
    f32x4 acc[16];
    #pragma unroll
    for (int i = 0; i < 16; ++i) acc[i] = (f32x4){0.f, 0.f, 0.f, 0.f};
    for (int kt = 0; kt < 8; ++kt) {
        const int k0 = kt * 32;
        __syncthreads();
        {
            int m = tid >> 2, kc = tid & 3;
            *(bf16x8*)&As[m * 40 + kc * 8] =
                *(const bf16x8*)&Hid16[(size_t)(m0 + m) * 256 + k0 + kc * 8];
        }
        for (int i = tid; i < 1024; i += 256) {
            int n = i >> 2, kc = i & 3;
            *(bf16x8*)&Ws[n * 40 + kc * 8] =
                *(const bf16x8*)&W16[OFF_WD2 + (size_t)n * 256 + k0 + kc * 8];
        }
        __syncthreads();
        bf16x8 af = *(const bf16x8*)&As[(w * 16 + ln) * 40 + quad * 8];
        #pragma unroll
        for (int nt = 0; nt < 16; ++nt) {
            bf16x8 bf = *(const bf16x8*)&Ws[(nt * 16 + ln) * 40 + quad * 8];
            acc[nt] = __builtin_amdgcn_mfma_f32_16x16x32_bf16(af, bf, acc[nt], 0, 0, 0);
        }
    }
    __syncthreads();
    #pragma unroll
    for (int nt = 0; nt < 16; ++nt)
        #pragma unroll
        for (int r = 0; r < 4; ++r)
            Clds[(w * 16 + quad * 4 + r) * 264 + nt * 16 + ln] = f2bf(acc[nt][r]);
    __syncthreads();

    // ---- Phase 2: gate GEMM from Clds ----
    f32x4 acc2[16];
    #pragma unroll
    for (int i = 0; i < 16; ++i) acc2[i] = (f32x4){0.f, 0.f, 0.f, 0.f};
    for (int kt = 0; kt < 8; ++kt) {
        const int k0 = kt * 32;
        __syncthreads();
        for (int i = tid; i < 1024; i += 256) {
            int n = i >> 2, kc = i & 3;
            *(bf16x8*)&Ws[n * 40 + kc * 8] =
                *(const bf16x8*)&W16[OFF_WG + (size_t)n * 256 + k0 + kc * 8];
        }
        __syncthreads();
        bf16x8 af = *(const bf16x8*)&Clds[(w * 16 + ln) * 264 + k0 + quad * 8];
        #pragma unroll
        for (int nt = 0; nt < 16; ++nt) {
            bf16x8 bf = *(const bf16x8*)&Ws[(nt * 16 + ln) * 40 + quad * 8];
            acc2[nt] = __builtin_amdgcn_mfma_f32_16x16x32_bf16(af, bf, acc2[nt], 0, 0, 0);
        }
    }

    // ---- epilogue: gate + delta + residual, transpose to [B,C,N] ----
    float trs = tanhf(rs[0]);
    float* tileF = (float*)As;   // As+Ws contiguous? use Ws region (20.5KB>=16.9KB)
    tileF = (float*)Ws;
    const int b = m0 >> 12, p0l = m0 & 4095;
    const int rowb = m0 + w * 16 + quad * 4;
    for (int g = 0; g < 4; ++g) {
        __syncthreads();
        #pragma unroll
        for (int j = 0; j < 4; ++j) {
            int nt = g * 4 + j;
            int col = nt * 16 + ln;
            float wgl = bf2f(W16[OFF_WGL + col]);
            #pragma unroll
            for (int r = 0; r < 4; ++r) {
                int row = rowb + r;
                float mrow = mask[row];
                float logit = acc2[nt][r] + mrow * wgl;
                float gate = mrow / (1.0f + __expf(-logit));
                float corr = bf2f(Clds[(w * 16 + quad * 4 + r) * 264 + col]);
                tileF[(j * 16 + ln) * 66 + (w * 16 + quad * 4 + r)] = trs * gate * corr;
            }
        }
        __syncthreads();
        for (int e = tid; e < 4096; e += 256) {
            int ch = e >> 6, pos = e & 63;
            size_t o = ((size_t)b * CC + g * 64 + ch) * NN + p0l + pos;
            out[o] = x[o] + tileF[ch * 66 + pos];
        }
    }
}

// ---------------------------------------------------------------------------
extern "C" void kernel_launch(void* const* d_in, const int* in_sizes, int n_in,
                              void* d_out, int out_size, void* d_ws, size_t ws_size,
                              hipStream_t stream) {
    const float* x     = (const float*)d_in[0];
    const float* mask  = (const float*)d_in[1];
    const float* gamma = (const float*)d_in[2];
    const float* beta  = (const float*)d_in[3];
    const float* wq    = (const float*)d_in[4];
    const float* wk    = (const float*)d_in[5];
    const float* wv    = (const float*)d_in[6];
    const float* w_out = (const float*)d_in[7];
    const float* w_qm  = (const float*)d_in[8];
    const float* wd1   = (const float*)d_in[9];
    const float* wd2   = (const float*)d_in[10];
    const float* wg    = (const float*)d_in[11];
    const float* rs    = (const float*)d_in[12];
    float* out = (float*)d_out;

    const size_t NC = (size_t)NTOT * CC;
    const size_t NE = (size_t)NTOT * EE;
    short* Xn16  = (short*)d_ws;        // NC
    short* Xt16  = Xn16 + NC;           // NC
    short* Xnm16 = Xt16 + NC;           // NC
    short* Q16   = Xnm16 + NC;          // NE
    short* K16   = Q16 + NE;            // NE
    short* V16t  = K16 + NE;            // NC
    short* D1in  = V16t + NC;           // NC
    short* Hid16 = D1in + NC;           // NC
    short* W16   = Hid16 + NC;          // W16_TOTAL
    // ~57 MB total

    wconv_kernel<<<(W16_TOTAL + 255) / 256, 256, 0, stream>>>(wq, wk, wv, w_out,
                                                              wd1, wd2, wg, W16);
    ln_kernel<<<256, 256, 0, stream>>>(x, gamma, beta, mask, Xt16, Xn16, Xnm16);
    qkproj_kernel<<<256, 256, 0, stream>>>(Xn16, W16, mask, w_qm, Q16, K16);
    mgemm<16, 8, 2><<<256, 256, 0, stream>>>(Xt16, nullptr, W16 + OFF_WV, 256, V16t);
    attn3_kernel<<<1024, 256, 0, stream>>>(Q16, K16, V16t, mask, W16, Xt16, D1in);
    mgemm<16, 16, 4><<<256, 256, 0, stream>>>(D1in, Xnm16, W16 + OFF_WD1, 512, Hid16);
    final_kernel<<<256, 256, 0, stream>>>(Hid16, W16, mask, rs, x, out);
}

// Round 5
// 376.336 us; speedup vs baseline: 1.2761x; 1.2761x over previous
//
#include <hip/hip_runtime.h>
#include <hip/hip_bf16.h>
#include <math.h>

// Problem constants
#define BB 4
#define CC 256
#define NN 4096          // H*W
#define EE 96
#define NTOT (BB*NN)     // 16384 rows

typedef __attribute__((ext_vector_type(8))) short bf16x8;
typedef __attribute__((ext_vector_type(4))) float f32x4;

__device__ __forceinline__ short f2bf(float x) {
    __hip_bfloat16 h = __float2bfloat16(x);
    return *reinterpret_cast<short*>(&h);
}
__device__ __forceinline__ float bf2f(short s) {
    unsigned int u = ((unsigned int)(unsigned short)s) << 16;
    float f;
    __builtin_memcpy(&f, &u, 4);
    return f;
}
__device__ __forceinline__ float gelu_exact(float v) {
    return 0.5f * v * (1.0f + erff(v * 0.70710678118654752f));
}
// async global->LDS, 16B per lane; LDS dest = uniform base + lane*16
__device__ __forceinline__ void gld16(void* lds, const void* g) {
    __builtin_amdgcn_global_load_lds(
        (const __attribute__((address_space(1))) unsigned int*)g,
        (__attribute__((address_space(3))) unsigned int*)lds, 16, 0, 0);
}

// Weight arena offsets (shorts). wg split into 256-stride matrix + last col.
#define OFF_WQ  0
#define OFF_WK  24576
#define OFF_WV  49152
#define OFF_WO  114688
#define OFF_WD1 180224
#define OFF_WD2 311296
#define OFF_WG  376832
#define OFF_WGL 442368
#define W16_TOTAL 442624

// ---------------------------------------------------------------------------
// Weight fp32 -> bf16 converter
// ---------------------------------------------------------------------------
__global__ void wconv_kernel(const float* __restrict__ wq, const float* __restrict__ wk,
                             const float* __restrict__ wv, const float* __restrict__ wo,
                             const float* __restrict__ wd1, const float* __restrict__ wd2,
                             const float* __restrict__ wg, short* __restrict__ W16) {
    int i = blockIdx.x * 256 + threadIdx.x;
    if (i >= W16_TOTAL) return;
    float v;
    if      (i < OFF_WK)  v = wq[i];
    else if (i < OFF_WV)  v = wk[i - OFF_WK];
    else if (i < OFF_WO)  v = wv[i - OFF_WV];
    else if (i < OFF_WD1) v = wo[i - OFF_WO];
    else if (i < OFF_WD2) v = wd1[i - OFF_WD1];
    else if (i < OFF_WG)  v = wd2[i - OFF_WD2];
    else if (i < OFF_WGL) { int l = i - OFF_WG; v = wg[(l >> 8) * 257 + (l & 255)]; }
    else                  v = wg[(i - OFF_WGL) * 257 + 256];
    W16[i] = f2bf(v);
}

// ---------------------------------------------------------------------------
// Kernel 1: channel LayerNorm + transpose; emits bf16 Xt16, Xn16, Xnm16
// ---------------------------------------------------------------------------
__global__ void ln_kernel(const float* __restrict__ x,
                          const float* __restrict__ gamma,
                          const float* __restrict__ beta,
                          const float* __restrict__ mask,
                          short* __restrict__ Xt16, short* __restrict__ Xn16,
                          short* __restrict__ Xnm16) {
    __shared__ float tile[256 * 65];
    __shared__ float psum[4][64], psq[4][64];
    __shared__ float mu_s[64], rs_s[64], mk_s[64];
    __shared__ float gs[256], bs[256];
    const int b  = blockIdx.x >> 6;
    const int p0 = (blockIdx.x & 63) * 64;
    const int tid = threadIdx.x;
    const float* xb = x + (size_t)b * CC * NN;

    gs[tid] = gamma[tid];
    bs[tid] = beta[tid];
    #pragma unroll
    for (int i = 0; i < 16; ++i) {
        int idx = tid + i * 256;
        int c = idx >> 4, p4 = (idx & 15) * 4;
        float4 v = *(const float4*)&xb[(size_t)c * NN + p0 + p4];
        tile[c * 65 + p4]     = v.x;
        tile[c * 65 + p4 + 1] = v.y;
        tile[c * 65 + p4 + 2] = v.z;
        tile[c * 65 + p4 + 3] = v.w;
    }
    if (tid < 64) mk_s[tid] = mask[(size_t)b * NN + p0 + tid];
    __syncthreads();
    {
        int col = tid & 63, part = tid >> 6;
        float s = 0.f, sq = 0.f;
        for (int r = part * 64; r < part * 64 + 64; ++r) {
            float v = tile[r * 65 + col];
            s += v; sq += v * v;
        }
        psum[part][col] = s; psq[part][col] = sq;
    }
    __syncthreads();
    if (tid < 64) {
        float S  = psum[0][tid] + psum[1][tid] + psum[2][tid] + psum[3][tid];
        float SQ = psq[0][tid] + psq[1][tid] + psq[2][tid] + psq[3][tid];
        float mu = S / 256.0f;
        float var = SQ / 256.0f - mu * mu;
        mu_s[tid] = mu;
        rs_s[tid] = rsqrtf(var + 1e-5f);
    }
    __syncthreads();
    size_t rowbase = ((size_t)b * NN + p0) * CC;
    #pragma unroll
    for (int i = 0; i < 8; ++i) {
        int idx = tid + i * 256;
        int p = idx >> 5, c8 = (idx & 31) * 8;
        float mu = mu_s[p], rcp = rs_s[p], mk = mk_s[p];
        bf16x8 xt, xn, xm;
        #pragma unroll
        for (int j = 0; j < 8; ++j) {
            float v = tile[(c8 + j) * 65 + p];
            float n = (v - mu) * rcp * gs[c8 + j] + bs[c8 + j];
            xt[j] = f2bf(v); xn[j] = f2bf(n); xm[j] = f2bf(n * mk);
        }
        size_t o = rowbase + (size_t)p * CC + c8;
        *(bf16x8*)&Xt16[o]  = xt;
        *(bf16x8*)&Xn16[o]  = xn;
        *(bf16x8*)&Xnm16[o] = xm;
    }
}

// ---------------------------------------------------------------------------
// Kernel 2: fused Q+K projection + cosine norm -> bf16 Q16, K16.
// ---------------------------------------------------------------------------
__global__ __launch_bounds__(256) void qkproj_kernel(
    const short* __restrict__ Xn16, const short* __restrict__ W16,
    const float* __restrict__ mask, const float* __restrict__ w_qm,
    short* __restrict__ Q16, short* __restrict__ K16)
{
    __shared__ short As[64 * 40];
    __shared__ short Ws[192 * 40];
    const int tid = threadIdx.x;
    const int w = tid >> 6, lane = tid & 63, ln = lane & 15, quad = lane >> 4;
    const int m0 = blockIdx.x * 64;

    f32x4 acc[12];
    #pragma unroll
    for (int i = 0; i < 12; ++i) acc[i] = (f32x4){0.f, 0.f, 0.f, 0.f};

    for (int kt = 0; kt < 8; ++kt) {
        const int k0 = kt * 32;
        __syncthreads();
        {
            int m = tid >> 2, kc = tid & 3;
            *(bf16x8*)&As[m * 40 + kc * 8] =
                *(const bf16x8*)&Xn16[(size_t)(m0 + m) * 256 + k0 + kc * 8];
        }
        for (int i = tid; i < 768; i += 256) {
            int n = i >> 2, kc = i & 3;
            const short* src = (n < 96) ? &W16[OFF_WQ + (size_t)n * 256 + k0 + kc * 8]
                                        : &W16[OFF_WK + (size_t)(n - 96) * 256 + k0 + kc * 8];
            *(bf16x8*)&Ws[n * 40 + kc * 8] = *(const bf16x8*)src;
        }
        __syncthreads();
        bf16x8 af = *(const bf16x8*)&As[(w * 16 + ln) * 40 + quad * 8];
        #pragma unroll
        for (int nt = 0; nt < 12; ++nt) {
            bf16x8 bf = *(const bf16x8*)&Ws[(nt * 16 + ln) * 40 + quad * 8];
            acc[nt] = __builtin_amdgcn_mfma_f32_16x16x32_bf16(af, bf, acc[nt], 0, 0, 0);
        }
    }

    const int rowb = m0 + w * 16 + quad * 4;
    #pragma unroll
    for (int r = 0; r < 4; ++r) {
        int row = rowb + r;
        float mrow = mask[row];
        float q[6], k[6];
        float ssq = 0.f, ssk = 0.f;
        #pragma unroll
        for (int nt = 0; nt < 6; ++nt) {
            q[nt] = acc[nt][r] + mrow * w_qm[nt * 16 + ln];
            ssq += q[nt] * q[nt];
            k[nt] = acc[6 + nt][r];
            ssk += k[nt] * k[nt];
        }
        ssq += __shfl_xor(ssq, 1, 64); ssk += __shfl_xor(ssk, 1, 64);
        ssq += __shfl_xor(ssq, 2, 64); ssk += __shfl_xor(ssk, 2, 64);
        ssq += __shfl_xor(ssq, 4, 64); ssk += __shfl_xor(ssk, 4, 64);
        ssq += __shfl_xor(ssq, 8, 64); ssk += __shfl_xor(ssk, 8, 64);
        float sq = 1.0f / fmaxf(sqrtf(ssq), 1e-12f);
        float sk = 1.0f / fmaxf(sqrtf(ssk), 1e-12f);
        #pragma unroll
        for (int nt = 0; nt < 6; ++nt) {
            Q16[(size_t)row * EE + nt * 16 + ln] = f2bf(q[nt] * sq);
            K16[(size_t)row * EE + nt * 16 + ln] = f2bf(k[nt] * sk);
        }
    }
}

// ---------------------------------------------------------------------------
// Kernel 2b (template: V-proj MODE 2 transposed store, wd1 MODE 4 GELU)
// ---------------------------------------------------------------------------
template <int NT, int KT, int MODE>
__global__ __launch_bounds__(256) void mgemm(
    const short* __restrict__ A16, const short* __restrict__ A16b,
    const short* __restrict__ W16, int ldw,
    short* __restrict__ outb)
{
    constexpr int K = KT * 32;
    __shared__ short As[64 * 40];
    __shared__ short Ws[NT * 16 * 40];
    const int tid = threadIdx.x;
    const int w = tid >> 6, lane = tid & 63, ln = lane & 15, quad = lane >> 4;
    const int m0 = blockIdx.x * 64;

    f32x4 acc[NT];
    #pragma unroll
    for (int i = 0; i < NT; ++i) acc[i] = (f32x4){0.f, 0.f, 0.f, 0.f};

    for (int kt = 0; kt < KT; ++kt) {
        const int k0 = kt * 32;
        __syncthreads();
        {
            int m = tid >> 2, kc = tid & 3;
            int kk = k0 + kc * 8;
            const short* src;
            if (MODE == 4) {
                src = (kk < 256) ? &A16[(size_t)(m0 + m) * 256 + kk]
                                 : &A16b[(size_t)(m0 + m) * 256 + kk - 256];
            } else {
                src = &A16[(size_t)(m0 + m) * K + kk];
            }
            *(bf16x8*)&As[m * 40 + kc * 8] = *(const bf16x8*)src;
        }
        for (int i = tid; i < NT * 64; i += 256) {
            int n = i >> 2, kc = i & 3;
            *(bf16x8*)&Ws[n * 40 + kc * 8] =
                *(const bf16x8*)&W16[(size_t)n * ldw + k0 + kc * 8];
        }
        __syncthreads();
        bf16x8 af = *(const bf16x8*)&As[(w * 16 + ln) * 40 + quad * 8];
        #pragma unroll
        for (int nt = 0; nt < NT; ++nt) {
            bf16x8 bf = *(const bf16x8*)&Ws[(nt * 16 + ln) * 40 + quad * 8];
            acc[nt] = __builtin_amdgcn_mfma_f32_16x16x32_bf16(af, bf, acc[nt], 0, 0, 0);
        }
    }

    const int rowb = m0 + w * 16 + quad * 4;
    if (MODE == 4) {
        #pragma unroll
        for (int nt = 0; nt < NT; ++nt) {
            int col = nt * 16 + ln;
            #pragma unroll
            for (int r = 0; r < 4; ++r)
                outb[(size_t)(rowb + r) * 256 + col] = f2bf(gelu_exact(acc[nt][r]));
        }
    } else if (MODE == 2) {     // V: transpose to [B, C, N] bf16
        short* tileT = Ws;
        const int b = m0 >> 12, p0l = m0 & 4095;
        for (int g = 0; g < 4; ++g) {
            __syncthreads();
            #pragma unroll
            for (int j = 0; j < 4; ++j) {
                #pragma unroll
                for (int r = 0; r < 4; ++r)
                    tileT[(j * 16 + ln) * 66 + (w * 16 + quad * 4 + r)] =
                        f2bf(acc[g * 4 + j][r]);
            }
            __syncthreads();
            for (int e = tid; e < 2048; e += 256) {
                int ch = e >> 5, pp = (e & 31) * 2;
                unsigned lo = (unsigned short)tileT[ch * 66 + pp];
                unsigned hi = (unsigned short)tileT[ch * 66 + pp + 1];
                *(unsigned*)&outb[((size_t)b * CC + g * 64 + ch) * NN + p0l + pp] =
                    lo | (hi << 16);
            }
        }
    }
}

// ---------------------------------------------------------------------------
// Kernel 3: LDS-staged MFMA attention, partial-K version.
// Grid 768 = 3 key-groups x 256 q-tiles. Block 256 thr / 4 waves, 64 queries.
// All 4 waves SHARE the K/V LDS tiles (async global_load_lds staging).
// Wave w: S for q[w*16..), P->LDS; PV for all 64 q x ch[w*64..).
// Fixed-max softmax => partial (O,l) per key-group, reduced in wout2.
// LDS: V double-buffered [j][ch] chunk layout; K single [p][key]; P padded.
// ---------------------------------------------------------------------------
__global__ __launch_bounds__(256, 3) void attn4_kernel(
    const short* __restrict__ Q16, const short* __restrict__ K16,
    const short* __restrict__ V16t, const float* __restrict__ mask,
    short* __restrict__ Opart, float* __restrict__ Lpart)
{
    __shared__ short Vs[2][8192];     // [j 0..3][ch 0..255] chunks of 8 shorts
    __shared__ short Ks[3072];        // [p 0..11][key 0..31] chunks of 8 shorts
    __shared__ float flg[32];
    __shared__ short Ps[64 * 40];

    const int tid = threadIdx.x;
    const int w = tid >> 6, lane = tid & 63, ln = lane & 15, quad = lane >> 4;
    const int bidx = blockIdx.x;
    const int kg = bidx >> 8;                       // 0..2 key group
    const int qg = bidx & 255;
    const int b  = (qg & 7) >> 1;                   // XCD-pinned batch
    const int qt = ((qg >> 3) << 1) | (qg & 1);     // 0..63
    const int q0 = qt * 64;
    const size_t bN = (size_t)b * NN;
    const size_t bCC = (size_t)b * CC;
    const int kbase = kg * 1376;
    const int NIT = (kg == 2) ? 42 : 43;            // 1376/1376/1344 keys
    const float C1 = 1.02062072615966f;             // 10/sqrt(96)

    // Q fragments for this wave's 16 S-rows
    bf16x8 qf[3];
    #pragma unroll
    for (int e = 0; e < 3; ++e)
        qf[e] = *(const bf16x8*)&Q16[(bN + q0 + w * 16 + ln) * EE + e * 32 + quad * 8];

    f32x4 acc[4][4];                                 // [m-tile][n-tile]
    #pragma unroll
    for (int mt = 0; mt < 4; ++mt)
        #pragma unroll
        for (int nt = 0; nt < 4; ++nt) acc[mt][nt] = (f32x4){0.f, 0.f, 0.f, 0.f};
    float lsum[4] = {0.f, 0.f, 0.f, 0.f};

    const int wbase = w * 64;                        // wave-uniform lane base

    // ---- prologue: stage tile 0 (V->buf0, K, flg), drain ----
    {
        const int k0 = kbase;
        #pragma unroll
        for (int i = 0; i < 4; ++i)
            gld16(&Vs[0][(i * 256 + wbase) * 8],
                  &V16t[(bCC + tid) * NN + k0 + i * 8]);
        gld16(&Ks[wbase * 8], &K16[(bN + k0 + (tid & 31)) * EE + (tid >> 5) * 8]);
        if (w < 2)
            gld16(&Ks[(256 + wbase) * 8],
                  &K16[(bN + k0 + (tid & 31)) * EE + (8 + ((tid & 63) >> 5)) * 8]);
        if (w == 3 && lane < 8)
            gld16(&flg[0], &mask[bN + k0 + lane * 4]);
    }
    __syncthreads();

    for (int it = 0; it < NIT; ++it) {
        const int p = it & 1;
        // async V prefetch for next iter into the other buffer
        if (it + 1 < NIT) {
            const int k0n = kbase + (it + 1) * 32;
            #pragma unroll
            for (int i = 0; i < 4; ++i)
                gld16(&Vs[1 - p][(i * 256 + wbase) * 8],
                      &V16t[(bCC + tid) * NN + k0n + i * 8]);
        }

        // ---- S = Q K^T (K from LDS) ----
        f32x4 s0 = (f32x4){0.f,0.f,0.f,0.f}, s1 = s0;
        #pragma unroll
        for (int e = 0; e < 3; ++e) {
            bf16x8 kf0 = *(const bf16x8*)&Ks[((e * 4 + quad) * 32 + ln) * 8];
            bf16x8 kf1 = *(const bf16x8*)&Ks[((e * 4 + quad) * 32 + 16 + ln) * 8];
            s0 = __builtin_amdgcn_mfma_f32_16x16x32_bf16(qf[e], kf0, s0, 0, 0, 0);
            s1 = __builtin_amdgcn_mfma_f32_16x16x32_bf16(qf[e], kf1, s1, 0, 0, 0);
        }
        bool z0 = flg[ln] >= 0.5f;
        bool z1 = flg[16 + ln] >= 0.5f;
        #pragma unroll
        for (int r = 0; r < 4; ++r) {
            float p0 = z0 ? 0.f : __expf(fmaf(s0[r], C1, -C1));
            float p1 = z1 ? 0.f : __expf(fmaf(s1[r], C1, -C1));
            lsum[r] += p0 + p1;
            Ps[(w * 16 + quad * 4 + r) * 40 + ln]      = f2bf(p0);
            Ps[(w * 16 + quad * 4 + r) * 40 + 16 + ln] = f2bf(p1);
        }
        __syncthreads();                         // barrier1: P visible, K free

        // async K/flg prefetch (single-buffered: QK of this iter is done)
        if (it + 1 < NIT) {
            const int k0n = kbase + (it + 1) * 32;
            gld16(&Ks[wbase * 8], &K16[(bN + k0n + (tid & 31)) * EE + (tid >> 5) * 8]);
            if (w < 2)
                gld16(&Ks[(256 + wbase) * 8],
                      &K16[(bN + k0n + (tid & 31)) * EE + (8 + ((tid & 63) >> 5)) * 8]);
            if (w == 3 && lane < 8)
                gld16(&flg[0], &mask[bN + k0n + lane * 4]);
        }

        // ---- PV: all 64 q x this wave's 64 channels, V from LDS ----
        #pragma unroll
        for (int mt = 0; mt < 4; ++mt) {
            bf16x8 pf = *(const bf16x8*)&Ps[(mt * 16 + ln) * 40 + quad * 8];
            #pragma unroll
            for (int nt = 0; nt < 4; ++nt) {
                bf16x8 vf = *(const bf16x8*)&Vs[p][(quad * 256 + wbase + nt * 16 + ln) * 8];
                acc[mt][nt] = __builtin_amdgcn_mfma_f32_16x16x32_bf16(pf, vf, acc[mt][nt], 0, 0, 0);
            }
        }
        __syncthreads();                         // barrier2: drains DMAs, frees Ps
    }

    // ---- epilogue: write partial l and partial O (bf16) ----
    #pragma unroll
    for (int r = 0; r < 4; ++r) {
        float l = lsum[r];
        l += __shfl_xor(l, 1, 64); l += __shfl_xor(l, 2, 64);
        l += __shfl_xor(l, 4, 64); l += __shfl_xor(l, 8, 64);
        if (ln == 0)
            Lpart[(size_t)kg * NTOT + bN + q0 + w * 16 + quad * 4 + r] = l;
    }
    #pragma unroll
    for (int mt = 0; mt < 4; ++mt)
        #pragma unroll
        for (int nt = 0; nt < 4; ++nt)
            #pragma unroll
            for (int r = 0; r < 4; ++r)
                Opart[((size_t)kg * NTOT + bN + q0 + mt * 16 + quad * 4 + r) * 256
                      + w * 64 + nt * 16 + ln] = f2bf(acc[mt][nt][r]);
}

// ---------------------------------------------------------------------------
// Kernel 4: reduce 3 key-group partials + normalize + fused w_out - Xt -> D1in
// ---------------------------------------------------------------------------
__global__ __launch_bounds__(256) void wout2_kernel(
    const short* __restrict__ Opart, const float* __restrict__ Lpart,
    const short* __restrict__ W16, const short* __restrict__ Xt16,
    short* __restrict__ D1in)
{
    __shared__ short Olds[64 * 264];
    __shared__ float lsh[64];
    const int tid = threadIdx.x;
    const int w = tid >> 6, lane = tid & 63, ln = lane & 15, quad = lane >> 4;
    const int m0 = blockIdx.x * 64;

    if (tid < 64) {
        float l = Lpart[m0 + tid] + Lpart[NTOT + m0 + tid] + Lpart[2 * NTOT + m0 + tid];
        lsh[tid] = 1.0f / l;
    }
    __syncthreads();

    // sum partials, normalize, stage O in LDS (bf16)
    #pragma unroll
    for (int j = 0; j < 8; ++j) {
        int c = tid + j * 256;
        int q = c >> 5, ch8 = (c & 31) * 8;
        size_t base = (size_t)(m0 + q) * 256 + ch8;
        bf16x8 a = *(const bf16x8*)&Opart[base];
        bf16x8 bq = *(const bf16x8*)&Opart[(size_t)NTOT * 256 + base];
        bf16x8 cq = *(const bf16x8*)&Opart[(size_t)2 * NTOT * 256 + base];
        float linv = lsh[q];
        bf16x8 o;
        #pragma unroll
        for (int e = 0; e < 8; ++e)
            o[e] = f2bf((bf2f(a[e]) + bf2f(bq[e]) + bf2f(cq[e])) * linv);
        *(bf16x8*)&Olds[q * 264 + ch8] = o;
    }
    __syncthreads();

    // w_out GEMM: D1 = O @ wo^T - Xt ; wave w owns cols [w*64, w*64+64)
    f32x4 acc[4][4];
    #pragma unroll
    for (int mt = 0; mt < 4; ++mt)
        #pragma unroll
        for (int nt = 0; nt < 4; ++nt) acc[mt][nt] = (f32x4){0.f, 0.f, 0.f, 0.f};
    #pragma unroll
    for (int kt = 0; kt < 8; ++kt) {
        bf16x8 bf[4];
        #pragma unroll
        for (int nt = 0; nt < 4; ++nt)
            bf[nt] = *(const bf16x8*)&W16[OFF_WO + (size_t)(w * 64 + nt * 16 + ln) * 256
                                          + kt * 32 + quad * 8];
        #pragma unroll
        for (int mt = 0; mt < 4; ++mt) {
            bf16x8 af = *(const bf16x8*)&Olds[(mt * 16 + ln) * 264 + kt * 32 + quad * 8];
            #pragma unroll
            for (int nt = 0; nt < 4; ++nt)
                acc[mt][nt] = __builtin_amdgcn_mfma_f32_16x16x32_bf16(af, bf[nt], acc[mt][nt], 0, 0, 0);
        }
    }
    #pragma unroll
    for (int mt = 0; mt < 4; ++mt)
        #pragma unroll
        for (int nt = 0; nt < 4; ++nt)
            #pragma unroll
            for (int r = 0; r < 4; ++r) {
                size_t idx = (size_t)(m0 + mt * 16 + quad * 4 + r) * 256 + w * 64 + nt * 16 + ln;
                D1in[idx] = f2bf(acc[mt][nt][r] - bf2f(Xt16[idx]));
            }
}

// ---------------------------------------------------------------------------
// Kernel 5: fused wd2 + gate (wg) + residual writeback.
// ---------------------------------------------------------------------------
__global__ __launch_bounds__(256) void final_kernel(
    const short* __restrict__ Hid16, const short* __restrict__ W16,
    const float* __restrict__ mask, const float* __restrict__ rs,
    const float* __restrict__ x, float* __restrict__ out)
{
    __shared__ short As[64 * 40];
    __shared__ short Ws[256 * 40];
    __shared__ short Clds[64 * 264];
    const int tid = threadIdx.x;
    const int w = tid >> 6, lane = tid & 63, ln = lane & 15, quad = lane >> 4;
    const int m0 = blockIdx.x * 64;

    f32x4 acc[16];
    #pragma unroll
    for (int i = 0; i < 16; ++i) acc[i] = (f32x4){0.f, 0.f, 0.f, 0.f};
    for (int kt = 0; kt < 8; ++kt) {
        const int k0 = kt * 32;
        __syncthreads();
        {
            int m = tid >> 2, kc = tid & 3;
            *(bf16x8*)&As[m * 40 + kc * 8] =
                *(const bf16x8*)&Hid16[(size_t)(m0 + m) * 256 + k0 + kc * 8];
        }
        for (int i = tid; i < 1024; i += 256) {
            int n = i >> 2, kc = i & 3;
            *(bf16x8*)&Ws[n * 40 + kc * 8] =
                *(const bf16x8*)&W16[OFF_WD2 + (size_t)n * 256 + k0 + kc * 8];
        }
        __syncthreads();
        bf16x8 af = *(const bf16x8*)&As[(w * 16 + ln) * 40 + quad * 8];
        #pragma unroll
        for (int nt = 0; nt < 16; ++nt) {
            bf16x8 bf = *(const bf16x8*)&Ws[(nt * 16 + ln) * 40 + quad * 8];
            acc[nt] = __builtin_amdgcn_mfma_f32_16x16x32_bf16(af, bf, acc[nt], 0, 0, 0);
        }
    }
    __syncthreads();
    #pragma unroll
    for (int nt = 0; nt < 16; ++nt)
        #pragma unroll
        for (int r = 0; r < 4; ++r)
            Clds[(w * 16 + quad * 4 + r) * 264 + nt * 16 + ln] = f2bf(acc[nt][r]);
    __syncthreads();

    f32x4 acc2[16];
    #pragma unroll
    for (int i = 0; i < 16; ++i) acc2[i] = (f32x4){0.f, 0.f, 0.f, 0.f};
    for (int kt = 0; kt < 8; ++kt) {
        const int k0 = kt * 32;
        __syncthreads();
        for (int i = tid; i < 1024; i += 256) {
            int n = i >> 2, kc = i & 3;
            *(bf16x8*)&Ws[n * 40 + kc * 8] =
                *(const bf16x8*)&W16[OFF_WG + (size_t)n * 256 + k0 + kc * 8];
        }
        __syncthreads();
        bf16x8 af = *(const bf16x8*)&Clds[(w * 16 + ln) * 264 + k0 + quad * 8];
        #pragma unroll
        for (int nt = 0; nt < 16; ++nt) {
            bf16x8 bf = *(const bf16x8*)&Ws[(nt * 16 + ln) * 40 + quad * 8];
            acc2[nt] = __builtin_amdgcn_mfma_f32_16x16x32_bf16(af, bf, acc2[nt], 0, 0, 0);
        }
    }

    float trs = tanhf(rs[0]);
    float* tileF = (float*)Ws;
    const int b = m0 >> 12, p0l = m0 & 4095;
    const int rowb = m0 + w * 16 + quad * 4;
    for (int g = 0; g < 4; ++g) {
        __syncthreads();
        #pragma unroll
        for (int j = 0; j < 4; ++j) {
            int nt = g * 4 + j;
            int col = nt * 16 + ln;
            float wgl = bf2f(W16[OFF_WGL + col]);
            #pragma unroll
            for (int r = 0; r < 4; ++r) {
                int row = rowb + r;
                float mrow = mask[row];
                float logit = acc2[nt][r] + mrow * wgl;
                float gate = mrow / (1.0f + __expf(-logit));
                float corr = bf2f(Clds[(w * 16 + quad * 4 + r) * 264 + col]);
                tileF[(j * 16 + ln) * 66 + (w * 16 + quad * 4 + r)] = trs * gate * corr;
            }
        }
        __syncthreads();
        for (int e = tid; e < 4096; e += 256) {
            int ch = e >> 6, pos = e & 63;
            size_t o = ((size_t)b * CC + g * 64 + ch) * NN + p0l + pos;
            out[o] = x[o] + tileF[ch * 66 + pos];
        }
    }
}

// ---------------------------------------------------------------------------
extern "C" void kernel_launch(void* const* d_in, const int* in_sizes, int n_in,
                              void* d_out, int out_size, void* d_ws, size_t ws_size,
                              hipStream_t stream) {
    const float* x     = (const float*)d_in[0];
    const float* mask  = (const float*)d_in[1];
    const float* gamma = (const float*)d_in[2];
    const float* beta  = (const float*)d_in[3];
    const float* wq    = (const float*)d_in[4];
    const float* wk    = (const float*)d_in[5];
    const float* wv    = (const float*)d_in[6];
    const float* w_out = (const float*)d_in[7];
    const float* w_qm  = (const float*)d_in[8];
    const float* wd1   = (const float*)d_in[9];
    const float* wd2   = (const float*)d_in[10];
    const float* wg    = (const float*)d_in[11];
    const float* rs    = (const float*)d_in[12];
    float* out = (float*)d_out;

    const size_t NC = (size_t)NTOT * CC;
    const size_t NE = (size_t)NTOT * EE;
    short* Xn16  = (short*)d_ws;        // NC
    short* Xt16  = Xn16 + NC;           // NC
    short* Xnm16 = Xt16 + NC;           // NC
    short* Q16   = Xnm16 + NC;          // NE
    short* K16   = Q16 + NE;            // NE
    short* V16t  = K16 + NE;            // NC
    short* D1in  = V16t + NC;           // NC
    short* Hid16 = D1in + NC;           // NC
    short* W16   = Hid16 + NC;          // W16_TOTAL
    short* Opart = W16 + W16_TOTAL;     // 3*NC bf16
    float* Lpart = (float*)(Opart + 3 * NC);   // 3*NTOT f32
    // total ~83 MB (< 96.5 MB proven)

    wconv_kernel<<<(W16_TOTAL + 255) / 256, 256, 0, stream>>>(wq, wk, wv, w_out,
                                                              wd1, wd2, wg, W16);
    ln_kernel<<<256, 256, 0, stream>>>(x, gamma, beta, mask, Xt16, Xn16, Xnm16);
    qkproj_kernel<<<256, 256, 0, stream>>>(Xn16, W16, mask, w_qm, Q16, K16);
    mgemm<16, 8, 2><<<256, 256, 0, stream>>>(Xt16, nullptr, W16 + OFF_WV, 256, V16t);
    attn4_kernel<<<768, 256, 0, stream>>>(Q16, K16, V16t, mask, Opart, Lpart);
    wout2_kernel<<<256, 256, 0, stream>>>(Opart, Lpart, W16, Xt16, D1in);
    mgemm<16, 16, 4><<<256, 256, 0, stream>>>(D1in, Xnm16, W16 + OFF_WD1, 512, Hid16);
    final_kernel<<<256, 256, 0, stream>>>(Hid16, W16, mask, rs, x, out);
}

// Round 6
// 309.915 us; speedup vs baseline: 1.5496x; 1.2143x over previous
//
#include <hip/hip_runtime.h>
#include <hip/hip_bf16.h>
#include <math.h>

// Problem constants
#define BB 4
#define CC 256
#define NN 4096          // H*W
#define EE 96
#define NTOT (BB*NN)     // 16384 rows

typedef __attribute__((ext_vector_type(8))) short bf16x8;
typedef __attribute__((ext_vector_type(4))) float f32x4;

__device__ __forceinline__ short f2bf(float x) {
    __hip_bfloat16 h = __float2bfloat16(x);
    return *reinterpret_cast<short*>(&h);
}
__device__ __forceinline__ float bf2f(short s) {
    unsigned int u = ((unsigned int)(unsigned short)s) << 16;
    float f;
    __builtin_memcpy(&f, &u, 4);
    return f;
}
__device__ __forceinline__ float gelu_exact(float v) {
    return 0.5f * v * (1.0f + erff(v * 0.70710678118654752f));
}
// async global->LDS, 16B per lane; LDS dest = uniform base + lane*16
__device__ __forceinline__ void gld16(void* lds, const void* g) {
    __builtin_amdgcn_global_load_lds(
        (const __attribute__((address_space(1))) unsigned int*)g,
        (__attribute__((address_space(3))) unsigned int*)lds, 16, 0, 0);
}

// Weight arena offsets (shorts). wg split into 256-stride matrix + last col.
#define OFF_WQ  0
#define OFF_WK  24576
#define OFF_WV  49152
#define OFF_WO  114688
#define OFF_WD1 180224
#define OFF_WD2 311296
#define OFF_WG  376832
#define OFF_WGL 442368
#define W16_TOTAL 442624

// ---------------------------------------------------------------------------
// Weight fp32 -> bf16 converter
// ---------------------------------------------------------------------------
__global__ void wconv_kernel(const float* __restrict__ wq, const float* __restrict__ wk,
                             const float* __restrict__ wv, const float* __restrict__ wo,
                             const float* __restrict__ wd1, const float* __restrict__ wd2,
                             const float* __restrict__ wg, short* __restrict__ W16) {
    int i = blockIdx.x * 256 + threadIdx.x;
    if (i >= W16_TOTAL) return;
    float v;
    if      (i < OFF_WK)  v = wq[i];
    else if (i < OFF_WV)  v = wk[i - OFF_WK];
    else if (i < OFF_WO)  v = wv[i - OFF_WV];
    else if (i < OFF_WD1) v = wo[i - OFF_WO];
    else if (i < OFF_WD2) v = wd1[i - OFF_WD1];
    else if (i < OFF_WG)  v = wd2[i - OFF_WD2];
    else if (i < OFF_WGL) { int l = i - OFF_WG; v = wg[(l >> 8) * 257 + (l & 255)]; }
    else                  v = wg[(i - OFF_WGL) * 257 + 256];
    W16[i] = f2bf(v);
}

// ---------------------------------------------------------------------------
// Kernel 1: channel LayerNorm + transpose, 32-position tiles (4 blocks/CU).
// Emits bf16 Xt16 (= x, row-major) and Xn16 (normed).
// ---------------------------------------------------------------------------
__global__ __launch_bounds__(256) void ln_kernel(
    const float* __restrict__ x, const float* __restrict__ gamma,
    const float* __restrict__ beta,
    short* __restrict__ Xt16, short* __restrict__ Xn16) {
    __shared__ float tile[256 * 33];
    __shared__ float psum[8][32], psq[8][32];
    __shared__ float mu_s[32], rs_s[32];
    __shared__ float gs[256], bs[256];
    const int b  = blockIdx.x >> 7;
    const int p0 = (blockIdx.x & 127) * 32;
    const int tid = threadIdx.x;
    const float* xb = x + (size_t)b * CC * NN;

    gs[tid] = gamma[tid];
    bs[tid] = beta[tid];
    #pragma unroll
    for (int i = 0; i < 8; ++i) {
        int idx = tid + i * 256;
        int c = idx >> 3, p4 = (idx & 7) * 4;
        float4 v = *(const float4*)&xb[(size_t)c * NN + p0 + p4];
        tile[c * 33 + p4]     = v.x;
        tile[c * 33 + p4 + 1] = v.y;
        tile[c * 33 + p4 + 2] = v.z;
        tile[c * 33 + p4 + 3] = v.w;
    }
    __syncthreads();
    {
        int col = tid & 31, part = tid >> 5;
        float s = 0.f, sq = 0.f;
        for (int r = part * 32; r < part * 32 + 32; ++r) {
            float v = tile[r * 33 + col];
            s += v; sq += v * v;
        }
        psum[part][col] = s; psq[part][col] = sq;
    }
    __syncthreads();
    if (tid < 32) {
        float S = 0.f, SQ = 0.f;
        #pragma unroll
        for (int j = 0; j < 8; ++j) { S += psum[j][tid]; SQ += psq[j][tid]; }
        float mu = S / 256.0f;
        float var = SQ / 256.0f - mu * mu;
        mu_s[tid] = mu;
        rs_s[tid] = rsqrtf(var + 1e-5f);
    }
    __syncthreads();
    size_t rowbase = ((size_t)b * NN + p0) * CC;
    #pragma unroll
    for (int i = 0; i < 4; ++i) {
        int idx = tid + i * 256;
        int p = idx >> 5, c8 = (idx & 31) * 8;
        float mu = mu_s[p], rcp = rs_s[p];
        bf16x8 xt, xn;
        #pragma unroll
        for (int j = 0; j < 8; ++j) {
            float v = tile[(c8 + j) * 33 + p];
            float n = (v - mu) * rcp * gs[c8 + j] + bs[c8 + j];
            xt[j] = f2bf(v); xn[j] = f2bf(n);
        }
        size_t o = rowbase + (size_t)p * CC + c8;
        *(bf16x8*)&Xt16[o] = xt;
        *(bf16x8*)&Xn16[o] = xn;
    }
}

// ---------------------------------------------------------------------------
// Kernel 2: LDS-free Q+K projection + cosine norm. 32 rows/block, grid 512.
// Waves 0,1: Q for row-halves; waves 2,3: K. A/B frags direct from global.
// ---------------------------------------------------------------------------
__global__ __launch_bounds__(256) void qkproj_kernel(
    const short* __restrict__ Xn16, const short* __restrict__ W16,
    const float* __restrict__ mask, const float* __restrict__ w_qm,
    short* __restrict__ Q16, short* __restrict__ K16)
{
    const int tid = threadIdx.x;
    const int w = tid >> 6, lane = tid & 63, ln = lane & 15, quad = lane >> 4;
    const int m0 = blockIdx.x * 32 + (w & 1) * 16;
    const bool isQ = (w < 2);
    const int woff = isQ ? OFF_WQ : OFF_WK;

    f32x4 acc[6];
    #pragma unroll
    for (int i = 0; i < 6; ++i) acc[i] = (f32x4){0.f, 0.f, 0.f, 0.f};

    #pragma unroll
    for (int kt = 0; kt < 8; ++kt) {
        bf16x8 af = *(const bf16x8*)&Xn16[(size_t)(m0 + ln) * 256 + kt * 32 + quad * 8];
        #pragma unroll
        for (int nt = 0; nt < 6; ++nt) {
            bf16x8 bf = *(const bf16x8*)&W16[woff + (size_t)(nt * 16 + ln) * 256 + kt * 32 + quad * 8];
            acc[nt] = __builtin_amdgcn_mfma_f32_16x16x32_bf16(af, bf, acc[nt], 0, 0, 0);
        }
    }

    short* outp = isQ ? Q16 : K16;
    #pragma unroll
    for (int r = 0; r < 4; ++r) {
        int row = m0 + quad * 4 + r;
        float mrow = isQ ? mask[row] : 0.f;
        float vals[6];
        float ss = 0.f;
        #pragma unroll
        for (int nt = 0; nt < 6; ++nt) {
            float v = acc[nt][r];
            if (isQ) v += mrow * w_qm[nt * 16 + ln];
            vals[nt] = v;
            ss += v * v;
        }
        ss += __shfl_xor(ss, 1, 64); ss += __shfl_xor(ss, 2, 64);
        ss += __shfl_xor(ss, 4, 64); ss += __shfl_xor(ss, 8, 64);
        float sc = 1.0f / fmaxf(sqrtf(ss), 1e-12f);
        #pragma unroll
        for (int nt = 0; nt < 6; ++nt)
            outp[(size_t)row * EE + nt * 16 + ln] = f2bf(vals[nt] * sc);
    }
}

// ---------------------------------------------------------------------------
// Kernel 3: LDS-free V projection, transposed store to V16t [B,C,N].
// 32 rows/block, grid 512. GEMM direct-global; only the transpose uses LDS.
// ---------------------------------------------------------------------------
__global__ __launch_bounds__(256) void vproj_kernel(
    const short* __restrict__ Xt16, const short* __restrict__ W16,
    short* __restrict__ V16t)
{
    __shared__ short Vt[256 * 40];
    const int tid = threadIdx.x;
    const int w = tid >> 6, lane = tid & 63, ln = lane & 15, quad = lane >> 4;
    const int m0 = blockIdx.x * 32;
    const int wm = w >> 1, wn = w & 1;
    const int mrow = m0 + wm * 16;

    f32x4 acc[8];
    #pragma unroll
    for (int i = 0; i < 8; ++i) acc[i] = (f32x4){0.f, 0.f, 0.f, 0.f};

    #pragma unroll
    for (int kt = 0; kt < 8; ++kt) {
        bf16x8 af = *(const bf16x8*)&Xt16[(size_t)(mrow + ln) * 256 + kt * 32 + quad * 8];
        #pragma unroll
        for (int nt = 0; nt < 8; ++nt) {
            int col = wn * 128 + nt * 16 + ln;
            bf16x8 bf = *(const bf16x8*)&W16[OFF_WV + (size_t)col * 256 + kt * 32 + quad * 8];
            acc[nt] = __builtin_amdgcn_mfma_f32_16x16x32_bf16(af, bf, acc[nt], 0, 0, 0);
        }
    }
    #pragma unroll
    for (int nt = 0; nt < 8; ++nt) {
        int ch = wn * 128 + nt * 16 + ln;
        #pragma unroll
        for (int r = 0; r < 4; ++r)
            Vt[ch * 40 + wm * 16 + quad * 4 + r] = f2bf(acc[nt][r]);
    }
    __syncthreads();
    const int b = m0 >> 12, p0l = m0 & 4095;
    #pragma unroll
    for (int i = 0; i < 4; ++i) {
        int idx = tid + i * 256;
        int ch = idx >> 2, p8 = (idx & 3) * 8;
        *(bf16x8*)&V16t[((size_t)b * CC + ch) * NN + p0l + p8] =
            *(const bf16x8*)&Vt[ch * 40 + p8];
    }
}

// ---------------------------------------------------------------------------
// Kernel 4: LDS-staged MFMA attention, 4-way K-split, 4 blocks/CU.
// Grid 1024 = 4 key-groups x 256 q-tiles. 4 waves share K/V LDS tiles.
// Single-buffered V (DMA at iter top, drained by barrier1); K prefetch
// after barrier1, drained by barrier2. Fixed-max softmax -> associative.
// NOTE: K-staging p10/p11 bug from attn4 is FIXED (tid>>5, not (tid&63)>>5).
// ---------------------------------------------------------------------------
__global__ __launch_bounds__(256, 4) void attn_kernel(
    const short* __restrict__ Q16, const short* __restrict__ K16,
    const short* __restrict__ V16t, const float* __restrict__ mask,
    short* __restrict__ Opart, float* __restrict__ Lpart)
{
    __shared__ short Vs[8192];        // [j 0..3][ch 0..255] chunks of 8 shorts
    __shared__ short Ks[3072];        // [p 0..11][key 0..31] chunks of 8 shorts
    __shared__ short Ps[64 * 40];
    __shared__ float flg[32];

    const int tid = threadIdx.x;
    const int w = tid >> 6, lane = tid & 63, ln = lane & 15, quad = lane >> 4;
    const int bidx = blockIdx.x;
    const int kg = bidx >> 8;                       // 0..3 key group
    const int qg = bidx & 255;
    const int b  = (qg & 7) >> 1;                   // XCD-pinned batch
    const int qt = ((qg >> 3) << 1) | (qg & 1);     // 0..63
    const int q0 = qt * 64;
    const size_t bN = (size_t)b * NN;
    const size_t bCC = (size_t)b * CC;
    const int kbase = kg * 1024;
    const float C1 = 1.02062072615966f;             // 10/sqrt(96)
    const int wbase = w * 64;

    bf16x8 qf[3];
    #pragma unroll
    for (int e = 0; e < 3; ++e)
        qf[e] = *(const bf16x8*)&Q16[(bN + q0 + w * 16 + ln) * EE + e * 32 + quad * 8];

    f32x4 acc[4][4];
    #pragma unroll
    for (int mt = 0; mt < 4; ++mt)
        #pragma unroll
        for (int nt = 0; nt < 4; ++nt) acc[mt][nt] = (f32x4){0.f, 0.f, 0.f, 0.f};
    float lsum[4] = {0.f, 0.f, 0.f, 0.f};

    // prologue: K(0) + flg(0)
    gld16(&Ks[wbase * 8], &K16[(bN + kbase + (tid & 31)) * EE + (tid >> 5) * 8]);
    if (w < 2)
        gld16(&Ks[(256 + wbase) * 8],
              &K16[(bN + kbase + (tid & 31)) * EE + (8 + (tid >> 5)) * 8]);
    if (w == 3 && lane < 8)
        gld16(&flg[0], &mask[bN + kbase + lane * 4]);
    __syncthreads();

    for (int it = 0; it < 32; ++it) {
        const int k0 = kbase + it * 32;
        // V(it) DMA into the single buffer (PV of it-1 finished at barrier2)
        #pragma unroll
        for (int i = 0; i < 4; ++i)
            gld16(&Vs[(i * 256 + wbase) * 8], &V16t[(bCC + tid) * NN + k0 + i * 8]);

        // ---- S = Q K^T (K from LDS) ----
        f32x4 s0 = (f32x4){0.f,0.f,0.f,0.f}, s1 = s0;
        #pragma unroll
        for (int e = 0; e < 3; ++e) {
            bf16x8 kf0 = *(const bf16x8*)&Ks[((e * 4 + quad) * 32 + ln) * 8];
            bf16x8 kf1 = *(const bf16x8*)&Ks[((e * 4 + quad) * 32 + 16 + ln) * 8];
            s0 = __builtin_amdgcn_mfma_f32_16x16x32_bf16(qf[e], kf0, s0, 0, 0, 0);
            s1 = __builtin_amdgcn_mfma_f32_16x16x32_bf16(qf[e], kf1, s1, 0, 0, 0);
        }
        bool z0 = flg[ln] >= 0.5f;
        bool z1 = flg[16 + ln] >= 0.5f;
        #pragma unroll
        for (int r = 0; r < 4; ++r) {
            float p0 = z0 ? 0.f : __expf(fmaf(s0[r], C1, -C1));
            float p1 = z1 ? 0.f : __expf(fmaf(s1[r], C1, -C1));
            lsum[r] += p0 + p1;
            Ps[(w * 16 + quad * 4 + r) * 40 + ln]      = f2bf(p0);
            Ps[(w * 16 + quad * 4 + r) * 40 + 16 + ln] = f2bf(p1);
        }
        __syncthreads();        // barrier1: drains V(it); Ps visible; Ks free

        // K(it+1)/flg(it+1) prefetch (drained by barrier2)
        if (it + 1 < 32) {
            const int k0n = k0 + 32;
            gld16(&Ks[wbase * 8], &K16[(bN + k0n + (tid & 31)) * EE + (tid >> 5) * 8]);
            if (w < 2)
                gld16(&Ks[(256 + wbase) * 8],
                      &K16[(bN + k0n + (tid & 31)) * EE + (8 + (tid >> 5)) * 8]);
            if (w == 3 && lane < 8)
                gld16(&flg[0], &mask[bN + k0n + lane * 4]);
        }

        // ---- PV: all 64 q x this wave's 64 channels ----
        #pragma unroll
        for (int mt = 0; mt < 4; ++mt) {
            bf16x8 pf = *(const bf16x8*)&Ps[(mt * 16 + ln) * 40 + quad * 8];
            #pragma unroll
            for (int nt = 0; nt < 4; ++nt) {
                bf16x8 vf = *(const bf16x8*)&Vs[(quad * 256 + wbase + nt * 16 + ln) * 8];
                acc[mt][nt] = __builtin_amdgcn_mfma_f32_16x16x32_bf16(pf, vf, acc[mt][nt], 0, 0, 0);
            }
        }
        __syncthreads();        // barrier2: drains K(it+1); frees Ps/Vs
    }

    // ---- epilogue: partial l and partial O ----
    #pragma unroll
    for (int r = 0; r < 4; ++r) {
        float l = lsum[r];
        l += __shfl_xor(l, 1, 64); l += __shfl_xor(l, 2, 64);
        l += __shfl_xor(l, 4, 64); l += __shfl_xor(l, 8, 64);
        if (ln == 0)
            Lpart[(size_t)kg * NTOT + bN + q0 + w * 16 + quad * 4 + r] = l;
    }
    #pragma unroll
    for (int mt = 0; mt < 4; ++mt)
        #pragma unroll
        for (int nt = 0; nt < 4; ++nt)
            #pragma unroll
            for (int r = 0; r < 4; ++r)
                Opart[((size_t)kg * NTOT + bN + q0 + mt * 16 + quad * 4 + r) * 256
                      + wbase + nt * 16 + ln] = f2bf(acc[mt][nt][r]);
}

// ---------------------------------------------------------------------------
// Kernel 5: mega-fused epilogue. 32 rows/block, grid 512 (2 blocks/CU).
// P1: O = (sum of 4 Opart)/l -> Olds; Xnm -> Dlds upper.
// P2: D1 = O@wo^T - Xt -> Dlds lower.  P3: Hid = gelu([D1|Xnm]@wd1^T) -> Hlds.
// P4: Cor = Hid@wd2^T -> Clds.  P5: gate GEMM + delta -> tileB; out = x+delta.
// Weights read direct from L2 (no staging, no in-GEMM barriers).
// ---------------------------------------------------------------------------
__global__ __launch_bounds__(256, 2) void epi_kernel(
    const short* __restrict__ Opart, const float* __restrict__ Lpart,
    const short* __restrict__ W16, const short* __restrict__ Xt16,
    const short* __restrict__ Xn16, const float* __restrict__ mask,
    const float* __restrict__ rs, const float* __restrict__ x,
    float* __restrict__ out)
{
    __shared__ char lds[54400];
    short* Olds  = (short*)lds;              // stride 264, rows 0..31 (P1-P2)
    short* Hlds  = (short*)lds;              // stride 264 (P3-P4, Olds dead)
    short* Dlds  = (short*)(lds + 16896);    // stride 528, [D1 | Xnm] (P1-P3)
    short* Clds  = (short*)(lds + 16896);    // stride 264 (P4+, Dlds dead)
    short* tileB = (short*)(lds + 33792);    // 256 x 40 (P5, upper arena dead)
    float* lsh   = (float*)(lds + 54272);    // 32

    const int tid = threadIdx.x;
    const int w = tid >> 6, lane = tid & 63, ln = lane & 15, quad = lane >> 4;
    const int wm = w >> 1, wn = w & 1;
    const int m0 = blockIdx.x * 32;
    const int b = m0 >> 12, p0l = m0 & 4095;

    if (tid < 32) {
        int g = m0 + tid;
        lsh[tid] = 1.0f / (Lpart[g] + Lpart[NTOT + g] + Lpart[2 * NTOT + g] + Lpart[3 * NTOT + g]);
    }
    __syncthreads();

    // ---- P1 ----
    #pragma unroll
    for (int i = 0; i < 4; ++i) {
        int idx = tid + i * 256;
        int q = idx >> 5, ch8 = (idx & 31) * 8;
        size_t base = (size_t)(m0 + q) * 256 + ch8;
        bf16x8 a0 = *(const bf16x8*)&Opart[base];
        bf16x8 a1 = *(const bf16x8*)&Opart[(size_t)NTOT * 256 + base];
        bf16x8 a2 = *(const bf16x8*)&Opart[(size_t)2 * NTOT * 256 + base];
        bf16x8 a3 = *(const bf16x8*)&Opart[(size_t)3 * NTOT * 256 + base];
        float linv = lsh[q];
        bf16x8 o;
        #pragma unroll
        for (int e = 0; e < 8; ++e)
            o[e] = f2bf((bf2f(a0[e]) + bf2f(a1[e]) + bf2f(a2[e]) + bf2f(a3[e])) * linv);
        *(bf16x8*)&Olds[q * 264 + ch8] = o;
        bf16x8 xn = *(const bf16x8*)&Xn16[base];
        float mq = mask[m0 + q];
        bf16x8 xm;
        #pragma unroll
        for (int e = 0; e < 8; ++e) xm[e] = f2bf(bf2f(xn[e]) * mq);
        *(bf16x8*)&Dlds[q * 528 + 256 + ch8] = xm;
    }
    __syncthreads();

    // ---- P2: D1 = O@wo^T - Xt ----
    {
        f32x4 acc[8];
        #pragma unroll
        for (int i = 0; i < 8; ++i) acc[i] = (f32x4){0.f, 0.f, 0.f, 0.f};
        #pragma unroll
        for (int kt = 0; kt < 8; ++kt) {
            bf16x8 af = *(const bf16x8*)&Olds[(wm * 16 + ln) * 264 + kt * 32 + quad * 8];
            #pragma unroll
            for (int nt = 0; nt < 8; ++nt) {
                int col = wn * 128 + nt * 16 + ln;
                bf16x8 bf = *(const bf16x8*)&W16[OFF_WO + (size_t)col * 256 + kt * 32 + quad * 8];
                acc[nt] = __builtin_amdgcn_mfma_f32_16x16x32_bf16(af, bf, acc[nt], 0, 0, 0);
            }
        }
        #pragma unroll
        for (int nt = 0; nt < 8; ++nt) {
            int col = wn * 128 + nt * 16 + ln;
            #pragma unroll
            for (int r = 0; r < 4; ++r) {
                int row = wm * 16 + quad * 4 + r;
                float v = acc[nt][r] - bf2f(Xt16[(size_t)(m0 + row) * 256 + col]);
                Dlds[row * 528 + col] = f2bf(v);
            }
        }
    }
    __syncthreads();

    // ---- P3: Hid = gelu([D1|Xnm] @ wd1^T) ----
    {
        f32x4 acc[8];
        #pragma unroll
        for (int i = 0; i < 8; ++i) acc[i] = (f32x4){0.f, 0.f, 0.f, 0.f};
        #pragma unroll
        for (int kt = 0; kt < 16; ++kt) {
            bf16x8 af = *(const bf16x8*)&Dlds[(wm * 16 + ln) * 528 + kt * 32 + quad * 8];
            #pragma unroll
            for (int nt = 0; nt < 8; ++nt) {
                int col = wn * 128 + nt * 16 + ln;
                bf16x8 bf = *(const bf16x8*)&W16[OFF_WD1 + (size_t)col * 512 + kt * 32 + quad * 8];
                acc[nt] = __builtin_amdgcn_mfma_f32_16x16x32_bf16(af, bf, acc[nt], 0, 0, 0);
            }
        }
        __syncthreads();   // Olds reads done block-wide before Hlds overwrite
        #pragma unroll
        for (int nt = 0; nt < 8; ++nt) {
            int col = wn * 128 + nt * 16 + ln;
            #pragma unroll
            for (int r = 0; r < 4; ++r) {
                int row = wm * 16 + quad * 4 + r;
                Hlds[row * 264 + col] = f2bf(gelu_exact(acc[nt][r]));
            }
        }
    }
    __syncthreads();

    // ---- P4: Cor = Hid @ wd2^T ----
    {
        f32x4 acc[8];
        #pragma unroll
        for (int i = 0; i < 8; ++i) acc[i] = (f32x4){0.f, 0.f, 0.f, 0.f};
        #pragma unroll
        for (int kt = 0; kt < 8; ++kt) {
            bf16x8 af = *(const bf16x8*)&Hlds[(wm * 16 + ln) * 264 + kt * 32 + quad * 8];
            #pragma unroll
            for (int nt = 0; nt < 8; ++nt) {
                int col = wn * 128 + nt * 16 + ln;
                bf16x8 bf = *(const bf16x8*)&W16[OFF_WD2 + (size_t)col * 256 + kt * 32 + quad * 8];
                acc[nt] = __builtin_amdgcn_mfma_f32_16x16x32_bf16(af, bf, acc[nt], 0, 0, 0);
            }
        }
        __syncthreads();   // Dlds reads done before Clds overwrite
        #pragma unroll
        for (int nt = 0; nt < 8; ++nt) {
            int col = wn * 128 + nt * 16 + ln;
            #pragma unroll
            for (int r = 0; r < 4; ++r) {
                int row = wm * 16 + quad * 4 + r;
                Clds[row * 264 + col] = f2bf(acc[nt][r]);
            }
        }
    }
    __syncthreads();

    // ---- P5: gate GEMM + delta ----
    {
        f32x4 acc[8];
        #pragma unroll
        for (int i = 0; i < 8; ++i) acc[i] = (f32x4){0.f, 0.f, 0.f, 0.f};
        #pragma unroll
        for (int kt = 0; kt < 8; ++kt) {
            bf16x8 af = *(const bf16x8*)&Clds[(wm * 16 + ln) * 264 + kt * 32 + quad * 8];
            #pragma unroll
            for (int nt = 0; nt < 8; ++nt) {
                int col = wn * 128 + nt * 16 + ln;
                bf16x8 bf = *(const bf16x8*)&W16[OFF_WG + (size_t)col * 256 + kt * 32 + quad * 8];
                acc[nt] = __builtin_amdgcn_mfma_f32_16x16x32_bf16(af, bf, acc[nt], 0, 0, 0);
            }
        }
        float trs = tanhf(rs[0]);
        #pragma unroll
        for (int nt = 0; nt < 8; ++nt) {
            int col = wn * 128 + nt * 16 + ln;
            float wgl = bf2f(W16[OFF_WGL + col]);
            #pragma unroll
            for (int r = 0; r < 4; ++r) {
                int row = wm * 16 + quad * 4 + r;
                float mrow = mask[m0 + row];
                float logit = acc[nt][r] + mrow * wgl;
                float gate = mrow / (1.0f + __expf(-logit));
                float corr = bf2f(Clds[row * 264 + col]);
                tileB[col * 40 + row] = f2bf(trs * gate * corr);
            }
        }
    }
    __syncthreads();

    // ---- store: out[b,ch,p] = x + delta ----
    #pragma unroll
    for (int i = 0; i < 4; ++i) {
        int idx = tid + i * 256;
        int ch = idx >> 2, p8 = (idx & 3) * 8;
        bf16x8 d = *(const bf16x8*)&tileB[ch * 40 + p8];
        size_t o = ((size_t)b * CC + ch) * NN + p0l + p8;
        float4 x0 = *(const float4*)&x[o];
        float4 x1 = *(const float4*)&x[o + 4];
        float4 o0, o1;
        o0.x = x0.x + bf2f(d[0]); o0.y = x0.y + bf2f(d[1]);
        o0.z = x0.z + bf2f(d[2]); o0.w = x0.w + bf2f(d[3]);
        o1.x = x1.x + bf2f(d[4]); o1.y = x1.y + bf2f(d[5]);
        o1.z = x1.z + bf2f(d[6]); o1.w = x1.w + bf2f(d[7]);
        *(float4*)&out[o] = o0;
        *(float4*)&out[o + 4] = o1;
    }
}

// ---------------------------------------------------------------------------
extern "C" void kernel_launch(void* const* d_in, const int* in_sizes, int n_in,
                              void* d_out, int out_size, void* d_ws, size_t ws_size,
                              hipStream_t stream) {
    const float* x     = (const float*)d_in[0];
    const float* mask  = (const float*)d_in[1];
    const float* gamma = (const float*)d_in[2];
    const float* beta  = (const float*)d_in[3];
    const float* wq    = (const float*)d_in[4];
    const float* wk    = (const float*)d_in[5];
    const float* wv    = (const float*)d_in[6];
    const float* w_out = (const float*)d_in[7];
    const float* w_qm  = (const float*)d_in[8];
    const float* wd1   = (const float*)d_in[9];
    const float* wd2   = (const float*)d_in[10];
    const float* wg    = (const float*)d_in[11];
    const float* rs    = (const float*)d_in[12];
    float* out = (float*)d_out;

    const size_t NC = (size_t)NTOT * CC;
    const size_t NE = (size_t)NTOT * EE;
    short* Xn16  = (short*)d_ws;        // NC
    short* Xt16  = Xn16 + NC;           // NC
    short* Q16   = Xt16 + NC;           // NE
    short* K16   = Q16 + NE;            // NE
    short* V16t  = K16 + NE;            // NC
    short* W16   = V16t + NC;           // W16_TOTAL
    short* Opart = W16 + W16_TOTAL;     // 4*NC
    float* Lpart = (float*)(Opart + 4 * NC);   // 4*NTOT f32
    // ~66 MB total

    wconv_kernel<<<(W16_TOTAL + 255) / 256, 256, 0, stream>>>(wq, wk, wv, w_out,
                                                              wd1, wd2, wg, W16);
    ln_kernel<<<512, 256, 0, stream>>>(x, gamma, beta, Xt16, Xn16);
    qkproj_kernel<<<512, 256, 0, stream>>>(Xn16, W16, mask, w_qm, Q16, K16);
    vproj_kernel<<<512, 256, 0, stream>>>(Xt16, W16, V16t);
    attn_kernel<<<1024, 256, 0, stream>>>(Q16, K16, V16t, mask, Opart, Lpart);
    epi_kernel<<<512, 256, 0, stream>>>(Opart, Lpart, W16, Xt16, Xn16, mask,
                                        rs, x, out);
}